// Round 7
// baseline (289.640 us; speedup 1.0000x reference)
//
#include <hip/hip_runtime.h>
#include <hip/hip_bf16.h>
#include <cstdint>

typedef __bf16 bf16x8 __attribute__((ext_vector_type(8)));
typedef float f32x4 __attribute__((ext_vector_type(4)));
typedef short short8 __attribute__((ext_vector_type(8)));

__device__ __forceinline__ float bf2f(unsigned short u) {
  union { unsigned int i; float f; } x; x.i = ((unsigned int)u) << 16; return x.f;
}
__device__ __forceinline__ unsigned short f2bf(float f) {
  __hip_bfloat16 h = __float2bfloat16(f);
  return __builtin_bit_cast(unsigned short, h);
}

__device__ __forceinline__ void gload_lds16(const void* g, void* l) {
  auto gp = reinterpret_cast<__attribute__((address_space(1))) char*>(
      reinterpret_cast<uintptr_t>(g));
  auto lp = reinterpret_cast<__attribute__((address_space(3))) char*>(
      reinterpret_cast<uintptr_t>(l));
  __builtin_amdgcn_global_load_lds(gp, lp, 16, 0, 0);
}

// T1: bijective XCD-aware block swizzle (requires total blocks % 8 == 0)
__device__ __forceinline__ void xcd_swz(int& bx, int& by, int& bz) {
  const int gx = gridDim.x, gy = gridDim.y;
  const int n = gx * gy * (int)gridDim.z;
  int lin = blockIdx.x + gx * (blockIdx.y + gy * blockIdx.z);
  lin = (lin & 7) * (n >> 3) + (lin >> 3);
  bx = lin % gx; lin /= gx;
  by = lin % gy; bz = lin / gy;
}

// ---------- all 4 weight transposes in one launch ----------
__global__ void transpose_w4(const float* __restrict__ w0,
                             const float* __restrict__ w1,
                             const float* __restrict__ w2,
                             const float* __restrict__ w3,
                             unsigned short* __restrict__ out) {
  const int z = blockIdx.z;
  const float* in = (z == 0) ? w0 : (z == 1) ? w1 : (z == 2) ? w2 : w3;
  out += (size_t)z * 1024 * 1024;
  __shared__ float tile[32][33];
  const int c0 = blockIdx.x * 32, r0 = blockIdx.y * 32;
  tile[threadIdx.y][threadIdx.x] =
      in[(size_t)(r0 + threadIdx.y) * 1024 + c0 + threadIdx.x];
  __syncthreads();
  out[(size_t)(c0 + threadIdx.y) * 1024 + r0 + threadIdx.x] =
      f2bf(tile[threadIdx.x][threadIdx.y]);
}

__global__ void concat_bias3(const float* a, const float* b, const float* c,
                             float* o) {
  int i = blockIdx.x * 256 + threadIdx.x;
  if (i >= 3072) return;
  o[i] = (i < 1024) ? a[i] : (i < 2048 ? b[i - 1024] : c[i - 2048]);
}

// =====================================================================
// gemm_qkv: round-6 gemm_hi structure (128x128, 4 waves, single-buf 32KB,
// XOR swizzle, high occupancy) with A = x read as FP32 + inline bf16 cvt
// (reg-staged, per-lane swizzled ds_write). Non-swapped MFMA; VSPLIT
// epilogue: n0>=2048 -> V written transposed to vt[b][d][s].
// =====================================================================
__global__ __launch_bounds__(256, 4) void gemm_qkv(
    const float* __restrict__ xf,            // [8192][1024]
    const unsigned short* __restrict__ Bt,   // Wall [3072][1024]
    unsigned short* __restrict__ C,          // QKVc [8192][2048]
    const float* __restrict__ bias,          // [3072]
    unsigned short* __restrict__ vt) {       // [4][1024][2048]
  int bx, by, bz;
  xcd_swz(bx, by, bz);
  const int n0 = bx << 7;
  const int m0 = by << 7;
  __shared__ __attribute__((aligned(16))) unsigned short As[128 * 64];
  __shared__ __attribute__((aligned(16))) unsigned short Bs[128 * 64];
  const int t = threadIdx.x;
  const int lane = t & 63;
  const int w = t >> 6;
  const int wm = w >> 1, wn = w & 1;
  const unsigned short* gB = Bt + (size_t)n0 * 1024;

  const int srow = lane >> 3;
  const int gcol8 = ((lane & 7) ^ srow) << 3;  // inverse-swizzled source col

  f32x4 acc[4][4];
  const f32x4 vz = {0.f, 0.f, 0.f, 0.f};
#pragma unroll
  for (int i = 0; i < 4; ++i)
#pragma unroll
    for (int j = 0; j < 4; ++j) acc[i][j] = vz;

  for (int kt = 0; kt < 16; ++kt) {
    const unsigned short* pB = gB + (size_t)kt * 64;
    const float* pA = xf + (size_t)m0 * 1024 + (size_t)kt * 64;
#pragma unroll
    for (int i = 0; i < 4; ++i) {
      const int r0 = (w << 3) + (i << 5);
      // B: async gload (bf16 weights)
      gload_lds16(pB + (size_t)(r0 + srow) * 1024 + gcol8, Bs + r0 * 64);
      // A: f32 load + cvt + swizzled per-lane LDS write
      const float* s = pA + (size_t)(r0 + srow) * 1024 + gcol8;
      const float4 a0 = *reinterpret_cast<const float4*>(s);
      const float4 a1 = *reinterpret_cast<const float4*>(s + 4);
      short8 pk;
      pk[0] = (short)f2bf(a0.x); pk[1] = (short)f2bf(a0.y);
      pk[2] = (short)f2bf(a0.z); pk[3] = (short)f2bf(a0.w);
      pk[4] = (short)f2bf(a1.x); pk[5] = (short)f2bf(a1.y);
      pk[6] = (short)f2bf(a1.z); pk[7] = (short)f2bf(a1.w);
      *reinterpret_cast<short8*>(As + (r0 + srow) * 64 + ((lane & 7) << 3)) = pk;
    }
    __syncthreads();

#pragma unroll
    for (int kk = 0; kk < 2; ++kk) {
      bf16x8 af[4], bg[4];
      const int ch = ((kk << 2) + (lane >> 4)) ^ (lane & 7);
#pragma unroll
      for (int m = 0; m < 4; ++m) {
        const int row = (wm << 6) + (m << 4) + (lane & 15);
        af[m] = *reinterpret_cast<const bf16x8*>(As + row * 64 + (ch << 3));
      }
#pragma unroll
      for (int n = 0; n < 4; ++n) {
        const int row = (wn << 6) + (n << 4) + (lane & 15);
        bg[n] = *reinterpret_cast<const bf16x8*>(Bs + row * 64 + (ch << 3));
      }
#pragma unroll
      for (int m = 0; m < 4; ++m)
#pragma unroll
        for (int n = 0; n < 4; ++n)
          acc[m][n] = __builtin_amdgcn_mfma_f32_16x16x32_bf16(
              af[m], bg[n], acc[m][n], 0, 0, 0);
    }
    __syncthreads();
  }

  // C/D (non-swapped): col = lane&15 (N), row = (lane>>4)*4 + i (M)
  const int crow0 = m0 + (wm << 6) + ((lane >> 4) << 2);
  const int ccol0 = n0 + (wn << 6) + (lane & 15);
  if (n0 >= 2048) {
    const int b = m0 >> 11;
#pragma unroll
    for (int mf = 0; mf < 4; ++mf) {
#pragma unroll
      for (int nf = 0; nf < 4; ++nf) {
        const int col = ccol0 + (nf << 4);
        const float bb = bias[col];
        const int d = col - 2048;
        const int s = (crow0 & 2047) + (mf << 4);
        ushort4 o;
        o.x = f2bf(acc[mf][nf][0] + bb);
        o.y = f2bf(acc[mf][nf][1] + bb);
        o.z = f2bf(acc[mf][nf][2] + bb);
        o.w = f2bf(acc[mf][nf][3] + bb);
        *reinterpret_cast<ushort4*>(vt + (((size_t)b << 10) + d) * 2048 + s) = o;
      }
    }
  } else {
#pragma unroll
    for (int mf = 0; mf < 4; ++mf) {
#pragma unroll
      for (int nf = 0; nf < 4; ++nf) {
        const int col = ccol0 + (nf << 4);
        const float bb = bias[col];
#pragma unroll
        for (int i = 0; i < 4; ++i) {
          const int row = crow0 + (mf << 4) + i;
          C[(size_t)row * 2048 + col] = f2bf(acc[mf][nf][i] + bb);
        }
      }
    }
  }
}

// =====================================================================
// gemm_hi: round-6 high-occupancy 128x128 GEMM (swapped MFMA, vec4 C).
// Used for scores (bf16 out) and out-proj (f32 out).
// =====================================================================
template <typename OutT, bool HAS_BIAS>
__global__ __launch_bounds__(256, 4) void gemm_hi(
    const unsigned short* __restrict__ A,
    const unsigned short* __restrict__ Bt,
    OutT* __restrict__ C,
    const float* __restrict__ bias,
    int K, int lda, int ldb, int ldc, float scale,
    long sA, long sB, long sC) {
  int bx, by, bz;
  xcd_swz(bx, by, bz);
  A  += (long)bz * sA;
  Bt += (long)bz * sB;
  C  += (long)bz * sC;
  const int n0 = bx << 7;
  const int m0 = by << 7;
  __shared__ __attribute__((aligned(16))) unsigned short As[128 * 64];
  __shared__ __attribute__((aligned(16))) unsigned short Bs[128 * 64];
  const int t = threadIdx.x;
  const int lane = t & 63;
  const int w = t >> 6;
  const int wm = w >> 1, wn = w & 1;
  const unsigned short* gA = A + (size_t)m0 * lda;
  const unsigned short* gB = Bt + (size_t)n0 * ldb;
  const int NT = K >> 6;

  const int srow = lane >> 3;
  const int scol = ((lane & 7) ^ srow) << 3;

  f32x4 acc[4][4];
  const f32x4 vz = {0.f, 0.f, 0.f, 0.f};
#pragma unroll
  for (int i = 0; i < 4; ++i)
#pragma unroll
    for (int j = 0; j < 4; ++j) acc[i][j] = vz;

  for (int kt = 0; kt < NT; ++kt) {
    const unsigned short* pA = gA + (size_t)kt * 64;
    const unsigned short* pB = gB + (size_t)kt * 64;
#pragma unroll
    for (int i = 0; i < 4; ++i) {
      const int r0 = (w << 3) + (i << 5);
      gload_lds16(pA + (size_t)(r0 + srow) * lda + scol, As + r0 * 64);
      gload_lds16(pB + (size_t)(r0 + srow) * ldb + scol, Bs + r0 * 64);
    }
    __syncthreads();

#pragma unroll
    for (int kk = 0; kk < 2; ++kk) {
      bf16x8 af[4], bg[4];
      const int ch = ((kk << 2) + (lane >> 4)) ^ (lane & 7);
#pragma unroll
      for (int m = 0; m < 4; ++m) {
        const int row = (wm << 6) + (m << 4) + (lane & 15);
        af[m] = *reinterpret_cast<const bf16x8*>(As + row * 64 + (ch << 3));
      }
#pragma unroll
      for (int n = 0; n < 4; ++n) {
        const int row = (wn << 6) + (n << 4) + (lane & 15);
        bg[n] = *reinterpret_cast<const bf16x8*>(Bs + row * 64 + (ch << 3));
      }
#pragma unroll
      for (int m = 0; m < 4; ++m)
#pragma unroll
        for (int n = 0; n < 4; ++n)
          acc[m][n] = __builtin_amdgcn_mfma_f32_16x16x32_bf16(
              bg[n], af[m], acc[m][n], 0, 0, 0);
    }
    __syncthreads();
  }

  const int mrow0 = m0 + (wm << 6) + (lane & 15);
  const int ncol0 = n0 + (wn << 6) + ((lane >> 4) << 2);
#pragma unroll
  for (int mf = 0; mf < 4; ++mf) {
    const int row = mrow0 + (mf << 4);
#pragma unroll
    for (int nf = 0; nf < 4; ++nf) {
      const int col = ncol0 + (nf << 4);
      float4 bb = {0.f, 0.f, 0.f, 0.f};
      if (HAS_BIAS) bb = *reinterpret_cast<const float4*>(bias + col);
      const f32x4 a = acc[mf][nf];
      if constexpr (sizeof(OutT) == 2) {
        ushort4 o;
        o.x = f2bf(a[0] * scale + bb.x);
        o.y = f2bf(a[1] * scale + bb.y);
        o.z = f2bf(a[2] * scale + bb.z);
        o.w = f2bf(a[3] * scale + bb.w);
        *reinterpret_cast<ushort4*>(&C[(size_t)row * ldc + col]) = o;
      } else {
        float4 o;
        o.x = a[0] * scale + bb.x;
        o.y = a[1] * scale + bb.y;
        o.z = a[2] * scale + bb.z;
        o.w = a[3] * scale + bb.w;
        *reinterpret_cast<float4*>(&C[(size_t)row * ldc + col]) = o;
      }
    }
  }
}

// =====================================================================
// gemm_pv: PV GEMM with FUSED ONLINE SOFTMAX (flash second half).
// out[b][s][d] = softmax_row(Sc[b][s][:]) @ V  via Vt[b][d][s'].
// 128x128 tile, 4 waves (2M x 2N), BK=64, 32 K-tiles.
// P-fragments reg-staged from raw scores (global bf16) with running
// (m,l) per row; rows are lane&15-local in BOTH the A-operand fragment
// and the swapped-D acc layout, so max/sum reduce = 2 shfl_xor and the
// rescale is per-lane scalar. V stays gload_lds-staged (XOR swizzle).
// =====================================================================
__global__ __launch_bounds__(256, 3) void gemm_pv(
    const unsigned short* __restrict__ Sc,  // [B][2048][2048] raw scores
    const unsigned short* __restrict__ Vt,  // [B][1024][2048]
    unsigned short* __restrict__ O) {       // [B][2048][1024]
  int bx, by, bz;
  xcd_swz(bx, by, bz);
  const unsigned short* P = Sc + (long)bz * 2048 * 2048;
  const unsigned short* V = Vt + (long)bz * 1024 * 2048;
  unsigned short* Ob = O + (long)bz * 2048 * 1024;
  const int n0 = bx << 7;  // d-tile
  const int m0 = by << 7;  // s-tile
  __shared__ __attribute__((aligned(16))) unsigned short Bs[128 * 64];
  const int t = threadIdx.x;
  const int lane = t & 63;
  const int w = t >> 6;
  const int wm = w >> 1, wn = w & 1;
  const int srow = lane >> 3;
  const int scol = ((lane & 7) ^ srow) << 3;
  const int chh = lane >> 4;  // 0..3 col-chunk

  f32x4 acc[4][4];
  const f32x4 vz = {0.f, 0.f, 0.f, 0.f};
#pragma unroll
  for (int i = 0; i < 4; ++i)
#pragma unroll
    for (int j = 0; j < 4; ++j) acc[i][j] = vz;
  float mrun[4] = {-1e30f, -1e30f, -1e30f, -1e30f};
  float lpart[4] = {0.f, 0.f, 0.f, 0.f};

  for (int kt = 0; kt < 32; ++kt) {
    // stage V tile (async)
    const unsigned short* pV = V + (size_t)kt * 64;
#pragma unroll
    for (int i = 0; i < 4; ++i) {
      const int r0 = (w << 3) + (i << 5);
      gload_lds16(pV + (size_t)(n0 + r0 + srow) * 2048 + scol, Bs + r0 * 64);
    }

    // P fragments: load raw scores, online softmax (overlaps V latency)
    bf16x8 af[4][2];
#pragma unroll
    for (int mf = 0; mf < 4; ++mf) {
      const int row = m0 + (wm << 6) + (mf << 4) + (lane & 15);
      const unsigned short* pr = P + (size_t)row * 2048 + kt * 64;
      const bf16x8 r0v = *reinterpret_cast<const bf16x8*>(pr + (chh << 3));
      const bf16x8 r1v = *reinterpret_cast<const bf16x8*>(pr + 32 + (chh << 3));
      float f[16];
#pragma unroll
      for (int j = 0; j < 8; ++j) { f[j] = (float)r0v[j]; f[8 + j] = (float)r1v[j]; }
      float px = f[0];
#pragma unroll
      for (int j = 1; j < 16; ++j) px = fmaxf(px, f[j]);
      px = fmaxf(px, __shfl_xor(px, 16, 64));
      px = fmaxf(px, __shfl_xor(px, 32, 64));
      const float mn = fmaxf(mrun[mf], px);
      const float sc = __expf(mrun[mf] - mn);
      mrun[mf] = mn;
      float ls = 0.f;
#pragma unroll
      for (int j = 0; j < 16; ++j) { f[j] = __expf(f[j] - mn); ls += f[j]; }
      lpart[mf] = lpart[mf] * sc + ls;
#pragma unroll
      for (int nf = 0; nf < 4; ++nf) {
        acc[mf][nf][0] *= sc; acc[mf][nf][1] *= sc;
        acc[mf][nf][2] *= sc; acc[mf][nf][3] *= sc;
      }
      short8 p0, p1;
#pragma unroll
      for (int j = 0; j < 8; ++j) {
        p0[j] = (short)f2bf(f[j]);
        p1[j] = (short)f2bf(f[8 + j]);
      }
      af[mf][0] = __builtin_bit_cast(bf16x8, p0);
      af[mf][1] = __builtin_bit_cast(bf16x8, p1);
    }

    __syncthreads();  // V tile resident
#pragma unroll
    for (int kk = 0; kk < 2; ++kk) {
      bf16x8 bg[4];
      const int ch = ((kk << 2) + chh) ^ (lane & 7);
#pragma unroll
      for (int n = 0; n < 4; ++n) {
        const int row = (wn << 6) + (n << 4) + (lane & 15);
        bg[n] = *reinterpret_cast<const bf16x8*>(Bs + row * 64 + (ch << 3));
      }
#pragma unroll
      for (int m = 0; m < 4; ++m)
#pragma unroll
        for (int n = 0; n < 4; ++n)
          acc[m][n] = __builtin_amdgcn_mfma_f32_16x16x32_bf16(
              bg[n], af[m][kk], acc[m][n], 0, 0, 0);
    }
    __syncthreads();  // protect Bs
  }

  // epilogue: divide by row-sum; swapped-D vec4 stores
  const int mrow0 = m0 + (wm << 6) + (lane & 15);
  const int ncol0 = n0 + (wn << 6) + (chh << 2);
#pragma unroll
  for (int mf = 0; mf < 4; ++mf) {
    float l = lpart[mf];
    l += __shfl_xor(l, 16, 64);
    l += __shfl_xor(l, 32, 64);
    const float inv = 1.f / l;
    const int row = mrow0 + (mf << 4);
#pragma unroll
    for (int nf = 0; nf < 4; ++nf) {
      const int col = ncol0 + (nf << 4);
      ushort4 o;
      o.x = f2bf(acc[mf][nf][0] * inv);
      o.y = f2bf(acc[mf][nf][1] * inv);
      o.z = f2bf(acc[mf][nf][2] * inv);
      o.w = f2bf(acc[mf][nf][3] * inv);
      *reinterpret_cast<ushort4*>(&Ob[(size_t)row * 1024 + col]) = o;
    }
  }
}

// ---------- launch ----------
extern "C" void kernel_launch(void* const* d_in, const int* in_sizes, int n_in,
                              void* d_out, int out_size, void* d_ws, size_t ws_size,
                              hipStream_t stream) {
  (void)in_sizes; (void)n_in; (void)out_size; (void)ws_size;
  const float* x  = (const float*)d_in[0];
  const float* Wq = (const float*)d_in[1];
  const float* bq = (const float*)d_in[2];
  const float* Wk = (const float*)d_in[3];
  const float* bk = (const float*)d_in[4];
  const float* Wv = (const float*)d_in[5];
  const float* bv = (const float*)d_in[6];
  const float* Wo = (const float*)d_in[7];
  const float* bo = (const float*)d_in[8];
  float* out = (float*)d_out;

  constexpr int B = 4, S = 2048, D = 1024;
  constexpr size_t MB = 1ull << 20;
  char* ws = (char*)d_ws;
  unsigned short* Wall = (unsigned short*)(ws + 0);        // 8MB [4][1024][1024]
  float*          bqkv = (float*)(ws + 8 * MB);            // 12KB
  unsigned short* QKVc = (unsigned short*)(ws + 9 * MB);   // 32MB [8192][2048] Q|K
  unsigned short* Vt   = (unsigned short*)(ws + 41 * MB);  // 16MB [4][1024][2048]
  unsigned short* Sc   = (unsigned short*)(ws + 57 * MB);  // 32MB raw scores
  unsigned short* AO   = (unsigned short*)(ws + 89 * MB);  // 16MB

  const float scale = 0.03125f;  // 1/sqrt(1024)

  transpose_w4<<<dim3(32, 32, 4), dim3(32, 32), 0, stream>>>(Wq, Wk, Wv, Wo, Wall);
  concat_bias3<<<12, 256, 0, stream>>>(bq, bk, bv, bqkv);

  // fused QKV projection from f32 x: Q|K -> QKVc, V -> Vt transposed
  gemm_qkv<<<dim3(24, 64, 1), 256, 0, stream>>>(x, Wall, QKVc, bqkv, Vt);

  // raw scores[b] = scale * Q[b] @ K[b]^T
  gemm_hi<unsigned short, false><<<dim3(16, 16, 4), 256, 0, stream>>>(
      QKVc + 0, QKVc + 1024, Sc, nullptr, D, 2048, 2048, S, scale,
      (long)S * 2048, (long)S * 2048, (long)S * S);

  // attn_out[b] = softmax(scores[b]) @ V[b]   (fused online softmax)
  gemm_pv<<<dim3(8, 16, 4), 256, 0, stream>>>(Sc, Vt, AO);

  // out = AO @ Wot^T + bo (fp32)
  gemm_hi<float, true><<<dim3(8, 64, 1), 256, 0, stream>>>(
      AO, Wall + 3 * 1024 * 1024, out, bo, D, D, D, D, 1.f, 0, 0, 0);
}